// Round 3
// baseline (2565.270 us; speedup 1.0000x reference)
//
#include <hip/hip_runtime.h>
#include <math.h>

// Problem constants (fixed by setup_inputs)
#define B_ 8
#define C_ 2
#define T_ 1440000
#define F_ 1408            // ceil((T+M)/M) with M=1024
#define R_ 22528           // B*C*F
#define TARGET_HI 2731     // bits > 2730.667  <=>  int bits >= 2731

// GEMM tiling
#define BM 128
#define BN 128
#define BK 16
#define LDP 132            // padded LDS row

// ws layout in floats: Cm[2048*1024] @0 ; w[2048] @2097152 ; coeffs/dq @2099200
#define W_OFF  2097152
#define CF_OFF 2099200

// ---------------------------------------------------------------- tables ----
// CRITICAL: reproduce the reference's float32 phase arithmetic EXACTLY.
// ref: (pi/M) [f64->f32 weak scalar] * (n+0.5+512) [f32] * (k+0.5) [f32],
// each product rounded to f32, then cos of that f32 phase. Phase error vs
// exact is up to ~1e-3 rad at phase~8000 — the table VALUES differ from the
// exact-reduced table by ~1e-3, which is semantic, not noise.
__global__ __launch_bounds__(256) void init_tables(float* __restrict__ ws) {
  int idx = blockIdx.x * 256 + threadIdx.x;
  if (idx < 2097152) {
    int n = idx >> 10, k = idx & 1023;
    const float c0 = (float)(M_PI / 1024.0);     // f32(pi/M)
    float a  = (float)n + 0.5f + 512.0f;          // exact in f32
    float t1 = c0 * a;                            // f32 round
    float ph = t1 * ((float)k + 0.5f);            // f32 round
    ws[idx] = (float)cos((double)ph);             // correctly-rounded cosf
  } else if (idx < 2097152 + 2048) {
    int n = idx - 2097152;
    const float c1 = (float)(M_PI / 2048.0);      // f32(pi/N)
    float ph = c1 * ((float)n + 0.5f);
    ws[W_OFF + n] = (float)sin((double)ph);
  }
}

// ----------------------------------------------------------- forward MDCT ---
// coeffs[r,k] = sum_n (audio*w)[n] * Cm[n,k], n ascending (matches np einsum
// sequential order class); r=(b*C+c)*F+f
__global__ __launch_bounds__(256) void fwd_mdct(const float* __restrict__ audio,
                                                const float* __restrict__ ws,
                                                float* __restrict__ coeffs) {
  __shared__ float As[BK][LDP];
  __shared__ float Bs[BK][LDP];
  const float* __restrict__ Cm = ws;
  const float* __restrict__ w  = ws + W_OFF;

  int tid = threadIdx.x;
  int tx = tid & 15, ty = tid >> 4;
  int rowTile = blockIdx.x * BM;
  int colTile = blockIdx.y * BN;

  int a_m  = tid >> 1;
  int a_k0 = (tid & 1) << 3;
  int r  = rowTile + a_m;
  int bc = r / F_;
  int f  = r - bc * F_;
  const float* __restrict__ aud = audio + (size_t)bc * T_;
  int jb = f * 1024 + a_k0 - 1024;  // t-index base (n - M)

  int b_kk = tid >> 4;
  int b_c0 = (tid & 15) << 3;

  float acc[8][8];
#pragma unroll
  for (int i = 0; i < 8; i++)
#pragma unroll
    for (int j = 0; j < 8; j++) acc[i][j] = 0.f;

  for (int kt = 0; kt < 2048; kt += BK) {
    float av[8];
    int t0 = jb + kt;
    if (t0 >= 0 && t0 + 8 <= T_) {
      float4 x0 = *(const float4*)(aud + t0);
      float4 x1 = *(const float4*)(aud + t0 + 4);
      av[0] = x0.x; av[1] = x0.y; av[2] = x0.z; av[3] = x0.w;
      av[4] = x1.x; av[5] = x1.y; av[6] = x1.z; av[7] = x1.w;
    } else {
#pragma unroll
      for (int i = 0; i < 8; i++) {
        int t = t0 + i;
        av[i] = (t >= 0 && t < T_) ? aud[t] : 0.f;
      }
    }
    float4 w0 = *(const float4*)(w + kt + a_k0);
    float4 w1 = *(const float4*)(w + kt + a_k0 + 4);
    av[0] *= w0.x; av[1] *= w0.y; av[2] *= w0.z; av[3] *= w0.w;
    av[4] *= w1.x; av[5] *= w1.y; av[6] *= w1.z; av[7] *= w1.w;

    const float* bp = Cm + (size_t)(kt + b_kk) * 1024 + colTile + b_c0;
    float4 b0 = *(const float4*)bp;
    float4 b1 = *(const float4*)(bp + 4);

    __syncthreads();
#pragma unroll
    for (int i = 0; i < 8; i++) As[a_k0 + i][a_m] = av[i];
    *(float4*)&Bs[b_kk][b_c0]     = b0;
    *(float4*)&Bs[b_kk][b_c0 + 4] = b1;
    __syncthreads();

#pragma unroll
    for (int kk = 0; kk < BK; kk++) {
      float a[8], b[8];
      *(float4*)&a[0] = *(const float4*)&As[kk][ty * 4];
      *(float4*)&a[4] = *(const float4*)&As[kk][64 + ty * 4];
      *(float4*)&b[0] = *(const float4*)&Bs[kk][tx * 4];
      *(float4*)&b[4] = *(const float4*)&Bs[kk][64 + tx * 4];
#pragma unroll
      for (int i = 0; i < 8; i++)
#pragma unroll
        for (int j = 0; j < 8; j++) acc[i][j] = fmaf(a[i], b[j], acc[i][j]);
    }
  }

#pragma unroll
  for (int i = 0; i < 8; i++) {
    int m = (i < 4) ? (ty * 4 + i) : (64 + ty * 4 + i - 4);
    size_t rb = (size_t)(rowTile + m) * 1024 + colTile;
    *(float4*)&coeffs[rb + tx * 4] =
        make_float4(acc[i][0], acc[i][1], acc[i][2], acc[i][3]);
    *(float4*)&coeffs[rb + 64 + tx * 4] =
        make_float4(acc[i][4], acc[i][5], acc[i][6], acc[i][7]);
  }
}

// --------------------------------------------- gain search + quant/dequant --
// One block per (b,f): 2048 coeffs (both channels), in-place -> dq. All f32,
// matching the reference's f32 ops (powf/exp2f/rintf, weak-scalar promotion).
__global__ __launch_bounds__(256) void quantize(float* __restrict__ cf) {
  int bf = blockIdx.x;
  int b = bf / F_, f = bf - b * F_;
  int tid = threadIdx.x;
  int i0 = tid << 3;          // element index in [0,2048)
  int c  = i0 >> 10;
  int k0 = i0 & 1023;
  float* p = cf + ((size_t)(b * C_ + c) * F_ + f) * 1024 + k0;

  float x[8];
  *(float4*)&x[0] = *(const float4*)p;
  *(float4*)&x[4] = *(const float4*)(p + 4);

  float ax75[8];
#pragma unroll
  for (int u = 0; u < 8; u++) ax75[u] = powf(fabsf(x[u]), 0.75f);

  __shared__ int wsum[4];
  int lane = tid & 63, wid = tid >> 6;
  int lo = 0, hi = 120;
#pragma unroll
  for (int it = 0; it < 8; it++) {
    int mid = (lo + hi) >> 1;
    float inv = exp2f(-0.1875f * (float)mid);  // -0.75*g/4, exact f32 arg
    int s = 0;
#pragma unroll
    for (int u = 0; u < 8; u++) {
      float qm = rintf(ax75[u] * inv);         // round-half-even = jnp.round
      s += (qm > 0.f) ? (int)(65 - __clzll((long long)qm))  // floor(log2)+2
                      : 1;
    }
#pragma unroll
    for (int off = 32; off > 0; off >>= 1) s += __shfl_down(s, off, 64);
    if (lane == 0) wsum[wid] = s;
    __syncthreads();
    int total = wsum[0] + wsum[1] + wsum[2] + wsum[3];
    if (total >= TARGET_HI) lo = mid + 1; else hi = mid;
    __syncthreads();
  }

  float scale = exp2f(0.25f * (float)hi);
#pragma unroll
  for (int u = 0; u < 8; u++) {
    float ax = fabsf(x[u]);
    float qs = powf(ax / scale + 1e-9f, 0.75f);  // f32 div, +EPS, f32 pow
    float q  = rintf(qs);
    float d  = powf(q, 4.0f / 3.0f) * scale;     // exponent = f32(4/3)
    x[u] = copysignf(d, x[u]);
  }
  *(float4*)p       = *(float4*)&x[0];
  *(float4*)(p + 4) = *(float4*)&x[4];
}

// ----------------------------------------------------------- inverse MDCT ---
// td[r,n] = (2/1024) * sum_k dq[r,k]*Cm[n,k]; out[bc*T + f*1024+n-1024] += td*w[n]
__global__ __launch_bounds__(256) void inv_mdct(const float* __restrict__ ws,
                                                float* __restrict__ out) {
  __shared__ float As[BK][LDP];
  __shared__ float Bs[BK][LDP];
  const float* __restrict__ Cm = ws;
  const float* __restrict__ w  = ws + W_OFF;
  const float* __restrict__ dq = ws + CF_OFF;

  int tid = threadIdx.x;
  int tx = tid & 15, ty = tid >> 4;
  int rowTile = blockIdx.x * BM;   // over R_
  int colTile = blockIdx.y * BN;   // over n (2048)

  int a_m  = tid >> 1;
  int a_k0 = (tid & 1) << 3;
  int b_nn = tid >> 1;
  int b_k0 = (tid & 1) << 3;

  float acc[8][8];
#pragma unroll
  for (int i = 0; i < 8; i++)
#pragma unroll
    for (int j = 0; j < 8; j++) acc[i][j] = 0.f;

  for (int kt = 0; kt < 1024; kt += BK) {
    const float* ap = dq + (size_t)(rowTile + a_m) * 1024 + kt + a_k0;
    float4 a0 = *(const float4*)ap;
    float4 a1 = *(const float4*)(ap + 4);
    const float* bp = Cm + (size_t)(colTile + b_nn) * 1024 + kt + b_k0;
    float4 c0 = *(const float4*)bp;
    float4 c1 = *(const float4*)(bp + 4);

    __syncthreads();
    As[a_k0 + 0][a_m] = a0.x; As[a_k0 + 1][a_m] = a0.y;
    As[a_k0 + 2][a_m] = a0.z; As[a_k0 + 3][a_m] = a0.w;
    As[a_k0 + 4][a_m] = a1.x; As[a_k0 + 5][a_m] = a1.y;
    As[a_k0 + 6][a_m] = a1.z; As[a_k0 + 7][a_m] = a1.w;
    Bs[b_k0 + 0][b_nn] = c0.x; Bs[b_k0 + 1][b_nn] = c0.y;
    Bs[b_k0 + 2][b_nn] = c0.z; Bs[b_k0 + 3][b_nn] = c0.w;
    Bs[b_k0 + 4][b_nn] = c1.x; Bs[b_k0 + 5][b_nn] = c1.y;
    Bs[b_k0 + 6][b_nn] = c1.z; Bs[b_k0 + 7][b_nn] = c1.w;
    __syncthreads();

#pragma unroll
    for (int kk = 0; kk < BK; kk++) {
      float a[8], b[8];
      *(float4*)&a[0] = *(const float4*)&As[kk][ty * 4];
      *(float4*)&a[4] = *(const float4*)&As[kk][64 + ty * 4];
      *(float4*)&b[0] = *(const float4*)&Bs[kk][tx * 4];
      *(float4*)&b[4] = *(const float4*)&Bs[kk][64 + tx * 4];
#pragma unroll
      for (int i = 0; i < 8; i++)
#pragma unroll
        for (int j = 0; j < 8; j++) acc[i][j] = fmaf(a[i], b[j], acc[i][j]);
    }
  }

  float wv[8];
#pragma unroll
  for (int j = 0; j < 8; j++) {
    int n = (j < 4) ? (tx * 4 + j) : (64 + tx * 4 + j - 4);
    wv[j] = w[colTile + n];
  }
  const float sc = 2.0f / 1024.0f;
#pragma unroll
  for (int i = 0; i < 8; i++) {
    int m = (i < 4) ? (ty * 4 + i) : (64 + ty * 4 + i - 4);
    int r = rowTile + m;
    int bc = r / F_;
    int f  = r - bc * F_;
    float* op = out + (size_t)bc * T_;
    int tb = f * 1024 - 1024 + colTile;
#pragma unroll
    for (int j = 0; j < 8; j++) {
      int n = (j < 4) ? (tx * 4 + j) : (64 + tx * 4 + j - 4);
      int t = tb + n;
      if (t >= 0 && t < T_) unsafeAtomicAdd(op + t, acc[i][j] * sc * wv[j]);
    }
  }
}

// ------------------------------------------------------------------ launch --
extern "C" void kernel_launch(void* const* d_in, const int* in_sizes, int n_in,
                              void* d_out, int out_size, void* d_ws, size_t ws_size,
                              hipStream_t stream) {
  const float* audio = (const float*)d_in[0];
  float* out = (float*)d_out;
  float* ws  = (float*)d_ws;

  hipMemsetAsync(d_out, 0, (size_t)out_size * sizeof(float), stream);
  init_tables<<<(2097152 + 2048 + 255) / 256, 256, 0, stream>>>(ws);
  fwd_mdct<<<dim3(R_ / BM, 1024 / BN), 256, 0, stream>>>(audio, ws, ws + CF_OFF);
  quantize<<<B_ * F_, 256, 0, stream>>>(ws + CF_OFF);
  inv_mdct<<<dim3(R_ / BM, 2048 / BN), 256, 0, stream>>>(ws, out);
}

// Round 4
// 1040.248 us; speedup vs baseline: 2.4660x; 2.4660x over previous
//
#include <hip/hip_runtime.h>
#include <math.h>

// Problem constants (fixed by setup_inputs)
#define B_ 8
#define C_ 2
#define T_ 1440000
#define F_ 1408            // ceil((T+M)/M) with M=1024
#define R_ 22528           // B*C*F
#define TARGET_HI 2731     // bits > 2730.667  <=>  int bits >= 2731

// ws byte offsets
#define OFF_CFH 0ull                     // f16 [k=1024][n=2048] hi   (4 MiB)
#define OFF_CFL (4ull << 20)             // f16 [k=1024][n=2048] lo   (4 MiB)
#define OFF_CIH (8ull << 20)             // f16 [n=2048][k=1024] hi   (4 MiB)
#define OFF_WF  (12ull << 20)            // f32 [2048]
#define OFF_CF  (13ull << 20)            // f32 [R_][1024] coeffs (92.3 MB)
#define OFF_DQ  (OFF_CF + (size_t)R_ * 1024 * 4)   // f16 [R_][1024] (46 MB)

typedef _Float16 f16x8 __attribute__((ext_vector_type(8)));
typedef float f32x16 __attribute__((ext_vector_type(16)));

__device__ inline f32x16 mfma16(f16x8 a, f16x8 b, f32x16 c) {
  return __builtin_amdgcn_mfma_f32_32x32x16_f16(a, b, c, 0, 0, 0);
}

// ---------------------------------------------------------------- tables ----
// CRITICAL: reproduce the reference's float32 phase arithmetic EXACTLY
// (f32(pi/M) * f32(n+512.5) -> f32 round -> * f32(k+0.5) -> f32 round -> cos).
// Table VALUES differ from exact-reduced cos by ~1e-3 — semantic, not noise.
// Then split each f32 value into f16 hi + f16 lo (residual ~2^-24 rel).
__global__ __launch_bounds__(256) void init_tables(char* wsb) {
  _Float16* cfh = (_Float16*)(wsb + OFF_CFH);
  _Float16* cfl = (_Float16*)(wsb + OFF_CFL);
  _Float16* cih = (_Float16*)(wsb + OFF_CIH);
  float*    wf  = (float*)(wsb + OFF_WF);
  int idx = blockIdx.x * 256 + threadIdx.x;
  if (idx < 2097152) {
    int n = idx >> 10, k = idx & 1023;
    const float c0 = (float)(M_PI / 1024.0);
    float a  = (float)n + 0.5f + 512.0f;
    float t1 = c0 * a;
    float ph = t1 * ((float)k + 0.5f);
    float cm = (float)cos((double)ph);          // correctly-rounded cosf
    _Float16 h = (_Float16)cm;
    _Float16 l = (_Float16)(cm - (float)h);
    cfh[(size_t)k * 2048 + n] = h;
    cfl[(size_t)k * 2048 + n] = l;
    cih[(size_t)n * 1024 + k] = h;
  } else if (idx < 2097152 + 2048) {
    int n = idx - 2097152;
    const float c1 = (float)(M_PI / 2048.0);
    float ph = c1 * ((float)n + 0.5f);
    wf[n] = (float)sin((double)ph);
  }
}

// ----------------------------------------------- forward MDCT (f16 3-prod) --
// coeffs[r,k] = sum_n v_n*Cm[n,k],  v = windowed audio (f32, split to f16 hi/lo)
// 3-product split GEMM: vh*ch + vh*cl + vl*ch  (error ~2^-22/term)
__global__ __launch_bounds__(256) void fwd_mfma(const float* __restrict__ audio,
                                                const char* __restrict__ wsb,
                                                float* __restrict__ coeffs) {
  __shared__ _Float16 Ah[128][40];
  __shared__ _Float16 Al[128][40];
  __shared__ _Float16 Bh[128][40];
  __shared__ _Float16 Bl[128][40];
  const _Float16* cfh = (const _Float16*)(wsb + OFF_CFH);
  const _Float16* cfl = (const _Float16*)(wsb + OFF_CFL);
  const float*    wf  = (const float*)(wsb + OFF_WF);

  int tid = threadIdx.x;
  int lane = tid & 63, wid = tid >> 6;
  int l31 = lane & 31, lHalf = lane >> 5;
  int waveM = wid >> 1, waveN = wid & 1;
  int rowTile = blockIdx.x * 128, colTile = blockIdx.y * 128;

  // staging coords: each thread handles 16 contiguous K-elements of one row
  int sRow = tid >> 1;
  int sSeg = (tid & 1) << 4;
  int r = rowTile + sRow, bc = r / F_, f = r - bc * F_;
  const float* __restrict__ aud = audio + (size_t)bc * T_;
  int tBase = (f << 10) - 1024 + sSeg;
  const _Float16* bhp = cfh + (size_t)(colTile + sRow) * 2048 + sSeg;
  const _Float16* blp = cfl + (size_t)(colTile + sRow) * 2048 + sSeg;

  f32x16 acc[2][2];
#pragma unroll
  for (int i = 0; i < 2; i++)
#pragma unroll
    for (int j = 0; j < 2; j++)
#pragma unroll
      for (int e = 0; e < 16; e++) acc[i][j][e] = 0.f;

  for (int kt = 0; kt < 2048; kt += 32) {
    // ---- A: load audio, window, split
    float av[16];
    int t0 = tBase + kt;
    if (t0 >= 0 && t0 + 16 <= T_) {
#pragma unroll
      for (int q = 0; q < 4; q++) {
        float4 x = *(const float4*)(aud + t0 + q * 4);
        av[q * 4 + 0] = x.x; av[q * 4 + 1] = x.y;
        av[q * 4 + 2] = x.z; av[q * 4 + 3] = x.w;
      }
    } else {
#pragma unroll
      for (int i = 0; i < 16; i++) {
        int t = t0 + i;
        av[i] = (t >= 0 && t < T_) ? aud[t] : 0.f;
      }
    }
    f16x8 vh[2], vl[2];
#pragma unroll
    for (int i = 0; i < 16; i++) {
      float v = av[i] * wf[kt + sSeg + i];
      _Float16 h = (_Float16)v;
      vh[i >> 3][i & 7] = h;
      vl[i >> 3][i & 7] = (_Float16)(v - (float)h);
    }
    // ---- B: table splits (32B per thread per split)
    float4 tb0 = *(const float4*)(bhp + kt);
    float4 tb1 = *(const float4*)(bhp + kt + 8);
    float4 tl0 = *(const float4*)(blp + kt);
    float4 tl1 = *(const float4*)(blp + kt + 8);

    __syncthreads();
    *(f16x8*)&Ah[sRow][sSeg]     = vh[0];
    *(f16x8*)&Ah[sRow][sSeg + 8] = vh[1];
    *(f16x8*)&Al[sRow][sSeg]     = vl[0];
    *(f16x8*)&Al[sRow][sSeg + 8] = vl[1];
    *(float4*)&Bh[sRow][sSeg]     = tb0;
    *(float4*)&Bh[sRow][sSeg + 8] = tb1;
    *(float4*)&Bl[sRow][sSeg]     = tl0;
    *(float4*)&Bl[sRow][sSeg + 8] = tl1;
    __syncthreads();

#pragma unroll
    for (int kc = 0; kc < 2; kc++) {
      int ko = kc * 16 + lHalf * 8;
      f16x8 a_h[2], a_l[2], b_h[2], b_l[2];
#pragma unroll
      for (int mi = 0; mi < 2; mi++) {
        a_h[mi] = *(const f16x8*)&Ah[waveM * 64 + mi * 32 + l31][ko];
        a_l[mi] = *(const f16x8*)&Al[waveM * 64 + mi * 32 + l31][ko];
      }
#pragma unroll
      for (int ni = 0; ni < 2; ni++) {
        b_h[ni] = *(const f16x8*)&Bh[waveN * 64 + ni * 32 + l31][ko];
        b_l[ni] = *(const f16x8*)&Bl[waveN * 64 + ni * 32 + l31][ko];
      }
#pragma unroll
      for (int mi = 0; mi < 2; mi++)
#pragma unroll
        for (int ni = 0; ni < 2; ni++) {
          acc[mi][ni] = mfma16(a_h[mi], b_h[ni], acc[mi][ni]);
          acc[mi][ni] = mfma16(a_h[mi], b_l[ni], acc[mi][ni]);
          acc[mi][ni] = mfma16(a_l[mi], b_h[ni], acc[mi][ni]);
        }
    }
  }

  // epilogue: C/D layout col=lane&31, row=(reg&3)+8*(reg>>2)+4*(lane>>5)
#pragma unroll
  for (int mi = 0; mi < 2; mi++)
#pragma unroll
    for (int ni = 0; ni < 2; ni++) {
      int col = colTile + waveN * 64 + ni * 32 + l31;
#pragma unroll
      for (int reg = 0; reg < 16; reg++) {
        int rowIn = (reg & 3) + 8 * (reg >> 2) + 4 * lHalf;
        int rr = rowTile + waveM * 64 + mi * 32 + rowIn;
        coeffs[(size_t)rr * 1024 + col] = acc[mi][ni][reg];
      }
    }
}

// --------------------------------------------- gain search + quant/dequant --
// One block per (b,f): 2048 coeffs (both channels). f32 decisions matching
// the reference exactly; dq written as f16 for the inverse MFMA GEMM.
__global__ __launch_bounds__(256) void quantize(const float* __restrict__ cf,
                                                _Float16* __restrict__ dqh) {
  int bf = blockIdx.x;
  int b = bf / F_, f = bf - b * F_;
  int tid = threadIdx.x;
  int i0 = tid << 3;
  int c  = i0 >> 10;
  int k0 = i0 & 1023;
  size_t base = ((size_t)(b * C_ + c) * F_ + f) * 1024 + k0;

  float x[8];
  *(float4*)&x[0] = *(const float4*)(cf + base);
  *(float4*)&x[4] = *(const float4*)(cf + base + 4);

  float ax75[8];
#pragma unroll
  for (int u = 0; u < 8; u++) ax75[u] = powf(fabsf(x[u]), 0.75f);

  __shared__ int wsum[4];
  int lane = tid & 63, wid = tid >> 6;
  int lo = 0, hi = 120;
#pragma unroll
  for (int it = 0; it < 8; it++) {
    int mid = (lo + hi) >> 1;
    float inv = exp2f(-0.1875f * (float)mid);
    int s = 0;
#pragma unroll
    for (int u = 0; u < 8; u++) {
      float qm = rintf(ax75[u] * inv);
      s += (qm > 0.f) ? (int)(65 - __clzll((long long)qm)) : 1;
    }
#pragma unroll
    for (int off = 32; off > 0; off >>= 1) s += __shfl_down(s, off, 64);
    if (lane == 0) wsum[wid] = s;
    __syncthreads();
    int total = wsum[0] + wsum[1] + wsum[2] + wsum[3];
    if (total >= TARGET_HI) lo = mid + 1; else hi = mid;
    __syncthreads();
  }

  float scale = exp2f(0.25f * (float)hi);
  _Float16 o[8];
#pragma unroll
  for (int u = 0; u < 8; u++) {
    float ax = fabsf(x[u]);
    float qs = powf(ax / scale + 1e-9f, 0.75f);
    float q  = rintf(qs);
    float d  = powf(q, 4.0f / 3.0f) * scale;
    o[u] = (_Float16)copysignf(d, x[u]);
  }
  *(f16x8*)(dqh + base) = *(f16x8*)o;
}

// --------------------------------------- inverse MDCT (f16 1-prod) + OLA ----
// td[r,n] = (2/1024)*sum_k dq[r,k]*Cm[n,k]; out[bc*T + f*1024+n-1024] += td*w[n]
__global__ __launch_bounds__(256) void inv_mfma(const char* __restrict__ wsb,
                                               float* __restrict__ out) {
  __shared__ _Float16 Ad[128][40];
  __shared__ _Float16 Bd[128][40];
  const _Float16* dqh = (const _Float16*)(wsb + OFF_DQ);
  const _Float16* cih = (const _Float16*)(wsb + OFF_CIH);
  const float*    wf  = (const float*)(wsb + OFF_WF);

  int tid = threadIdx.x;
  int lane = tid & 63, wid = tid >> 6;
  int l31 = lane & 31, lHalf = lane >> 5;
  int waveM = wid >> 1, waveN = wid & 1;
  int rowTile = blockIdx.x * 128, colTile = blockIdx.y * 128;

  int sRow = tid >> 1;
  int sSeg = (tid & 1) << 4;
  const _Float16* ap = dqh + (size_t)(rowTile + sRow) * 1024 + sSeg;
  const _Float16* bp = cih + (size_t)(colTile + sRow) * 1024 + sSeg;

  f32x16 acc[2][2];
#pragma unroll
  for (int i = 0; i < 2; i++)
#pragma unroll
    for (int j = 0; j < 2; j++)
#pragma unroll
      for (int e = 0; e < 16; e++) acc[i][j][e] = 0.f;

  for (int kt = 0; kt < 1024; kt += 32) {
    float4 ta0 = *(const float4*)(ap + kt);
    float4 ta1 = *(const float4*)(ap + kt + 8);
    float4 tb0 = *(const float4*)(bp + kt);
    float4 tb1 = *(const float4*)(bp + kt + 8);

    __syncthreads();
    *(float4*)&Ad[sRow][sSeg]     = ta0;
    *(float4*)&Ad[sRow][sSeg + 8] = ta1;
    *(float4*)&Bd[sRow][sSeg]     = tb0;
    *(float4*)&Bd[sRow][sSeg + 8] = tb1;
    __syncthreads();

#pragma unroll
    for (int kc = 0; kc < 2; kc++) {
      int ko = kc * 16 + lHalf * 8;
      f16x8 a0 = *(const f16x8*)&Ad[waveM * 64 + l31][ko];
      f16x8 a1 = *(const f16x8*)&Ad[waveM * 64 + 32 + l31][ko];
      f16x8 b0 = *(const f16x8*)&Bd[waveN * 64 + l31][ko];
      f16x8 b1 = *(const f16x8*)&Bd[waveN * 64 + 32 + l31][ko];
      acc[0][0] = mfma16(a0, b0, acc[0][0]);
      acc[0][1] = mfma16(a0, b1, acc[0][1]);
      acc[1][0] = mfma16(a1, b0, acc[1][0]);
      acc[1][1] = mfma16(a1, b1, acc[1][1]);
    }
  }

  const float sc = 2.0f / 1024.0f;
#pragma unroll
  for (int mi = 0; mi < 2; mi++)
#pragma unroll
    for (int ni = 0; ni < 2; ni++) {
      int n = colTile + waveN * 64 + ni * 32 + l31;
      float wv = wf[n] * sc;
#pragma unroll
      for (int reg = 0; reg < 16; reg++) {
        int rowIn = (reg & 3) + 8 * (reg >> 2) + 4 * lHalf;
        int rr = rowTile + waveM * 64 + mi * 32 + rowIn;
        int bc = rr / F_;
        int f  = rr - bc * F_;
        int t  = (f << 10) + n - 1024;
        if (t >= 0 && t < T_)
          unsafeAtomicAdd(out + (size_t)bc * T_ + t, acc[mi][ni][reg] * wv);
      }
    }
}

// ------------------------------------------------------------------ launch --
extern "C" void kernel_launch(void* const* d_in, const int* in_sizes, int n_in,
                              void* d_out, int out_size, void* d_ws, size_t ws_size,
                              hipStream_t stream) {
  const float* audio = (const float*)d_in[0];
  float* out = (float*)d_out;
  char* wsb  = (char*)d_ws;
  float*    cf  = (float*)(wsb + OFF_CF);
  _Float16* dqh = (_Float16*)(wsb + OFF_DQ);

  hipMemsetAsync(d_out, 0, (size_t)out_size * sizeof(float), stream);
  init_tables<<<(2097152 + 2048 + 255) / 256, 256, 0, stream>>>(wsb);
  fwd_mfma<<<dim3(R_ / 128, 1024 / 128), 256, 0, stream>>>(audio, wsb, cf);
  quantize<<<B_ * F_, 256, 0, stream>>>(cf, dqh);
  inv_mfma<<<dim3(R_ / 128, 2048 / 128), 256, 0, stream>>>(wsb, out);
}